// Round 27
// baseline (242.668 us; speedup 1.0000x reference)
//
#include <hip/hip_runtime.h>
#include <cstdint>
#include <cstddef>

// ReweightVLAD on MI355X.  CRN collapsed to cw = xs·PLt − mur·PW + t·Qt + PB + β
// (LN folded: xs = x·rstd, PL = lnw·P).  All three big GEMMs on MFMA.
// Round 27: k_cwg 2 m-tiles/wave — across R12-R26 k_cwg sat at 55-85µs under
// every schedule/occupancy change; the invariant was ~160 B loads per 192
// MFMAs.  Now each 8-load B group feeds 24 MFMAs (two A fragments), halving
// global B-load instructions and wave count.  Grid 98x16=1568 (8x196 swizzle),
// LDS 34.8KB, acc[2][4].  Only k_cwg changed.

#define N_   512
#define C_   512
#define S_   49
#define CS_  25088   // C_*S_

// ---- ws layout (float offsets) ----
#define OFF_WBS   0u
#define OFF_WBM   4608u
#define OFF_WBL   29696u
#define OFF_WBT   71168u
#define OFF_BETA  103936u
// [103952, 136720) free
#define OFF_PLTH  136720u      // bf16 fragment-packed [98 slab][8 kc][4 nf][64 lane][8]
#define OFF_PLTL  939536u      // = 1605632 shorts = 802816 fl each
#define OFF_QTH   1742352u
#define OFF_QTL   2545168u
#define OFF_PWTH  3347984u     // bf16 [64][512] = 16384 fl each (stores -PW)
#define OFF_PWTL  3364368u
// memset region [OFF_PLTH, 3380752) = 3244032 floats
#define OFF_PB    3380752u     // 64
#define OFF_PBP   3380816u     // 25088  [q][c]
#define OFF_MUR   3405904u     // 262144 fp32 [n][c]
#define OFF_XS    3668048u     // 12845056 fp32 [n][cs]
#define OFF_WR    3668048u     // aliases XS (dead after k_cwg); 512*64*64
#define OFF_CWP2  16513104u    // 98*512*64 = 3211264 fp32
#define OFF_WSUM  19724368u    // 32768
#define OFF_CENTT 19757136u    // 32768 fp32 centT[c][64]
#define OFF_CWF   19789904u    // 3-way split conv_w: h/m/l, 16384 fl EACH
#define OFF_SSQ2  19839056u    // 512*2*64 = 65536 fp32 ssq partials
// total = 19904592 floats ≈ 79.6 MB

typedef __attribute__((ext_vector_type(8))) short bf16x8;
typedef __attribute__((ext_vector_type(4))) float f32x4;

__device__ __forceinline__ float wave_sum64(float v) {
  #pragma unroll
  for (int off = 32; off; off >>= 1) v += __shfl_xor(v, off, 64);
  return v;
}

__device__ __forceinline__ void bsplit(float f, short& h, short& l) {
  unsigned u = __float_as_uint(f);
  h = (short)(u >> 16);
  float hf = __uint_as_float(u & 0xffff0000u);
  l = (short)(__float_as_uint(f - hf) >> 16);
}

__device__ __forceinline__ void bsplit3(float f, short& h, short& m, short& l) {
  unsigned u = __float_as_uint(f);
  h = (short)(u >> 16);
  float hf = __uint_as_float(u & 0xffff0000u);
  float r1 = f - hf;
  unsigned u1 = __float_as_uint(r1);
  m = (short)(u1 >> 16);
  float mf = __uint_as_float(u1 & 0xffff0000u);
  float r2 = r1 - mf;
  l = (short)(__float_as_uint(r2) >> 16);
}

// bilinear align_corners 7->20 matrix entry
__device__ __forceinline__ float m20val(int r, int p) {
  float pos = (float)(r * 6) / 19.0f;
  int lo = (int)floorf(pos);
  int hi = min(lo + 1, 6);
  float fr = pos - (float)lo;
  float v = 0.f;
  if (p == lo) v += 1.f - fr;
  if (p == hi) v += fr;
  return v;
}

// -------- 1. fold acc_w into conv weights; beta scalar --------
__global__ void k_wbar(const float* __restrict__ w_s, const float* __restrict__ w_m,
                       const float* __restrict__ w_l, const float* __restrict__ w_t,
                       const float* __restrict__ accw, const float* __restrict__ accb,
                       const float* __restrict__ b_s, const float* __restrict__ b_m,
                       const float* __restrict__ b_l, const float* __restrict__ b_t,
                       float* __restrict__ wbs, float* __restrict__ wbm,
                       float* __restrict__ wbl, float* __restrict__ wbt,
                       float* __restrict__ beta) {
  int id = blockIdx.x * 256 + threadIdx.x;      // [0, 103936) exact
  if (id == 0) {
    float b = accb[0];
    for (int o = 0; o < 32; ++o) b = fmaf(accw[o],      b_s[o], b);
    for (int o = 0; o < 32; ++o) b = fmaf(accw[32 + o], b_m[o], b);
    for (int o = 0; o < 20; ++o) b = fmaf(accw[64 + o], b_l[o], b);
    for (int o = 0; o < 16; ++o) b = fmaf(accw[84 + o], b_t[o], b);
    beta[0] = b;
  }
  if (id < 4608) {
    int c = id / 9, uv = id % 9;
    float a = 0.f;
    for (int o = 0; o < 32; ++o) a = fmaf(accw[o], w_s[(size_t)(o * 512 + c) * 9 + uv], a);
    wbs[id] = a;
  } else if (id < 29696) {
    int i2 = id - 4608; int c = i2 / 49, uv = i2 % 49;
    float a = 0.f;
    for (int o = 0; o < 32; ++o) a = fmaf(accw[32 + o], w_m[(size_t)(o * 512 + c) * 49 + uv], a);
    wbm[i2] = a;
  } else if (id < 71168) {
    int i2 = id - 29696; int c = i2 / 81, uv = i2 % 81;
    float a = 0.f;
    for (int o = 0; o < 20; ++o) a = fmaf(accw[64 + o], w_l[(size_t)(o * 512 + c) * 81 + uv], a);
    wbl[i2] = a;
  } else {
    int i2 = id - 71168; int c = i2 / 64, uv = i2 % 64;
    float a = 0.f;
    for (int o = 0; o < 16; ++o) a = fmaf(accw[84 + o], w_t[(size_t)(o * 512 + c) * 64 + uv], a);
    wbt[i2] = a;
  }
}

// -------- 2. conv_w -> 3-way split + fragment-packed; cent -> centT --------
__global__ void k_wt(const float* __restrict__ convw, const float* __restrict__ cent,
                     short* __restrict__ cwfh, short* __restrict__ cwfm,
                     short* __restrict__ cwfl, float* __restrict__ centT) {
  int id = blockIdx.x * 256 + threadIdx.x;   // [0, 65536)
  if (id < 32768) {
    int k = id >> 9, c = id & 511;
    short h, m, l; bsplit3(convw[(size_t)k * 512 + c], h, m, l);
    int kc = c >> 5, kg = (c >> 3) & 3, off = c & 7;
    int w = k >> 4, l15 = k & 15;
    int idx = ((kc * 4 + w) * 64 + kg * 16 + l15) * 8 + off;
    cwfh[idx] = h; cwfm[idx] = m; cwfl[idx] = l;
  } else {
    int id2 = id - 32768;
    int k = id2 & 63, c = id2 >> 6;
    centT[id2] = cent[(size_t)k * 512 + c];
  }
}

// -------- 3. LN stats + scaled copy: xs = x*rstd, mur = mu*rstd --------
__global__ void k_xs(const float* __restrict__ x, float* __restrict__ xs,
                     float* __restrict__ mur) {
  int idx = blockIdx.x * 256 + threadIdx.x;     // [0, 262144) = (n,c)
  const float* p = x + (size_t)idx * 49;
  float s1 = 0.f, s2 = 0.f;
  #pragma unroll
  for (int s = 0; s < 49; ++s) { float v = p[s]; s1 += v; s2 = fmaf(v, v, s2); }
  float m = s1 * (1.f / 49.f);
  float var = s2 * (1.f / 49.f) - m * m;
  float r = 1.f / sqrtf(var + 1e-5f);
  float* o = xs + (size_t)idx * 49;
  #pragma unroll
  for (int s = 0; s < 49; ++s) o[s] = p[s] * r;
  mur[idx] = m * r;
}

// -------- 4. buildP: block=c, LDS tile, fragment-packed B output,
//            fused PW/PB fold --------
__global__ void __launch_bounds__(512) k_buildP(
    const float* __restrict__ wbs, const float* __restrict__ wbm,
    const float* __restrict__ wbl, const float* __restrict__ wbt,
    const float* __restrict__ lnw, const float* __restrict__ lnb,
    short* __restrict__ plth, short* __restrict__ pltl,
    short* __restrict__ qth,  short* __restrict__ qtl,
    short* __restrict__ pwth, short* __restrict__ pwtl,
    float* __restrict__ pbp) {
  __shared__ float M[20][7];
  __shared__ float tP[49][50];
  __shared__ float tQ[49][50];
  int c = blockIdx.x;
  int tid = threadIdx.x;
  if (tid < 140) { int r = tid / 7, p = tid % 7; M[r][p] = m20val(r, p); }
  __syncthreads();

  const float* wbsr = wbs + c * 9;     // block-uniform -> s_load feed
  const float* wbmr = wbm + c * 49;
  const float* wblr = wbl + c * 81;
  const float* wbtr = wbt + c * 64;

  // compute tile: e = s*49 + q
  for (int e = tid; e < 2401; e += 512) {
    int s = e / 49, q = e % 49;
    int i = q / 7, j = q % 7, pp = s / 7, qq = s % 7;

    float sumP = 0.f;
    { // xs: 3x3, stride 3, pad 1
      float rv[3];
      #pragma unroll
      for (int v = 0; v < 3; ++v) { int col = j * 3 - 1 + v; rv[v] = ((unsigned)col < 20u) ? M[col][qq] : 0.f; }
      #pragma unroll
      for (int u = 0; u < 3; ++u) {
        int row = i * 3 - 1 + u; float ru = ((unsigned)row < 20u) ? M[row][pp] : 0.f;
        float a = wbsr[u * 3 + 0] * rv[0];
        a = fmaf(wbsr[u * 3 + 1], rv[1], a);
        a = fmaf(wbsr[u * 3 + 2], rv[2], a);
        sumP = fmaf(ru, a, sumP);
      }
    }
    { // xm: 7x7, stride 5, pad 9
      float rv[7];
      #pragma unroll
      for (int v = 0; v < 7; ++v) { int col = j * 5 - 9 + v; rv[v] = ((unsigned)col < 20u) ? M[col][qq] : 0.f; }
      #pragma unroll
      for (int u = 0; u < 7; ++u) {
        int row = i * 5 - 9 + u; float ru = ((unsigned)row < 20u) ? M[row][pp] : 0.f;
        float a = 0.f;
        #pragma unroll
        for (int v = 0; v < 7; ++v) a = fmaf(wbmr[u * 7 + v], rv[v], a);
        sumP = fmaf(ru, a, sumP);
      }
    }
    { // xl: 9x9, stride 2, pad 1
      float rv[9];
      #pragma unroll
      for (int v = 0; v < 9; ++v) { int col = j * 2 - 1 + v; rv[v] = ((unsigned)col < 20u) ? M[col][qq] : 0.f; }
      #pragma unroll
      for (int u = 0; u < 9; ++u) {
        int row = i * 2 - 1 + u; float ru = ((unsigned)row < 20u) ? M[row][pp] : 0.f;
        float a = 0.f;
        #pragma unroll
        for (int v = 0; v < 9; ++v) a = fmaf(wblr[u * 9 + v], rv[v], a);
        sumP = fmaf(ru, a, sumP);
      }
    }
    tP[s][q] = sumP;

    float sumQ = 0.f;
    { // tc: 8x8, stride 2, pad 0
      float rv[8];
      #pragma unroll
      for (int v = 0; v < 8; ++v) { int col = j * 2 + v; rv[v] = ((unsigned)col < 20u) ? M[col][qq] : 0.f; }
      #pragma unroll
      for (int u = 0; u < 8; ++u) {
        int row = i * 2 + u; float ru = ((unsigned)row < 20u) ? M[row][pp] : 0.f;
        float a = 0.f;
        #pragma unroll
        for (int v = 0; v < 8; ++v) a = fmaf(wbtr[u * 8 + v], rv[v], a);
        sumQ = fmaf(ru, a, sumQ);
      }
    }
    tQ[s][q] = sumQ;
  }
  __syncthreads();

  // transpose-out in MFMA fragment-packed order:
  for (int e = tid; e < 2401; e += 512) {
    int q = e / 49, s = e % 49;
    float pv = tP[s][q];
    float qv = tQ[s][q];
    int k = c * 49 + s;
    int slab = k >> 8;
    int kc = (k & 255) >> 5;
    int kg = (k >> 3) & 3;
    int off = k & 7;
    int nf = q >> 4, l15 = q & 15;
    size_t oidx = (size_t)slab * 16384 + kc * 2048 + nf * 512
                + (size_t)(kg * 16 + l15) * 8 + off;
    short h, l;
    bsplit(lnw[s] * pv, h, l); plth[oidx] = h; pltl[oidx] = l;
    bsplit(qv, h, l);          qth[oidx]  = h; qtl[oidx]  = l;
  }

  // fused fold: pw[q] = sum_s lnw*P, pb[q] = sum_s lnb*P
  if (tid < 49) {
    int q = tid;
    float pw = 0.f, pb = 0.f;
    #pragma unroll 7
    for (int s = 0; s < 49; ++s) {
      float p = tP[s][q];
      pw = fmaf(lnw[s], p, pw);
      pb = fmaf(lnb[s], p, pb);
    }
    short h, l; bsplit(-pw, h, l);
    pwth[q * 512 + c] = h;
    pwtl[q * 512 + c] = l;
    pbp[q * 512 + c] = pb;
  }
}

// -------- 5. PB[q] = sum_c PBp[q][c] --------
__global__ void k_pb(const float* __restrict__ pbp, float* __restrict__ PB) {
  int q = blockIdx.x, lane = threadIdx.x;   // grid 49 x 64
  float a = 0.f;
  for (int c = lane; c < 512; c += 64) a += pbp[q * 512 + c];
  a = wave_sum64(a);
  if (lane == 0) PB[q] = a;
}

// -------- 6. MFMA split-bf16 GEMM: cwp2[slab][n][64], 2 m-tiles/wave -------
template <int SA, int SB>
__device__ __forceinline__ void mf_chunk1(const float* __restrict__ A,
                                          const short* __restrict__ Bh,
                                          const short* __restrict__ Bl,
                                          int k, int mbase, int l15, int kg,
                                          f32x4 (&acc)[4]) {
  bf16x8 ah, al;
  {
    const float* ap = A + (size_t)(mbase + l15) * SA + k + kg * 8;
    float4 v0 = *reinterpret_cast<const float4*>(ap);
    float4 v1 = *reinterpret_cast<const float4*>(ap + 4);
    float f[8] = {v0.x, v0.y, v0.z, v0.w, v1.x, v1.y, v1.z, v1.w};
    #pragma unroll
    for (int jj = 0; jj < 8; ++jj) { short hh, ll; bsplit(f[jj], hh, ll); ah[jj] = hh; al[jj] = ll; }
  }
  #pragma unroll
  for (int nf = 0; nf < 4; ++nf) {
    size_t bo = (size_t)(nf * 16 + l15) * SB + k + kg * 8;
    bf16x8 bh = *reinterpret_cast<const bf16x8*>(Bh + bo);
    bf16x8 bl = *reinterpret_cast<const bf16x8*>(Bl + bo);
    acc[nf] = __builtin_amdgcn_mfma_f32_16x16x32_bf16(ah, bh, acc[nf], 0, 0, 0);
    acc[nf] = __builtin_amdgcn_mfma_f32_16x16x32_bf16(ah, bl, acc[nf], 0, 0, 0);
    acc[nf] = __builtin_amdgcn_mfma_f32_16x16x32_bf16(al, bh, acc[nf], 0, 0, 0);
  }
}

__global__ void __launch_bounds__(64) k_cwg(
    const float* __restrict__ xs, const float* __restrict__ tin,
    const float* __restrict__ mur,
    const short* __restrict__ plth, const short* __restrict__ pltl,
    const short* __restrict__ qth,  const short* __restrict__ qtl,
    const short* __restrict__ pwth, const short* __restrict__ pwtl,
    float* __restrict__ cwp2) {
  __shared__ float at[32 * 272];       // 34816 B, stride 272: 2-way banks (free)
  // bijective XCD chunk swizzle: 1568 = 8 * 196
  int wgid = (blockIdx.x & 7) * 196 + (blockIdx.x >> 3);
  int slab = wgid >> 4, mt = wgid & 15;  // 98 slabs x 16 m-tiles of 32 rows
  int lane = threadIdx.x;
  int l15 = lane & 15, kg = lane >> 4;
  int mbase = mt * 32;                   // two 16-row fragments per wave
  int k0 = slab * 256;

  f32x4 acc[2][4];
  #pragma unroll
  for (int m2 = 0; m2 < 2; ++m2)
    #pragma unroll
    for (int nf = 0; nf < 4; ++nf) acc[m2][nf] = (f32x4){0.f, 0.f, 0.f, 0.f};

  #pragma unroll 1
  for (int ph = 0; ph < 2; ++ph) {
    const float* A  = ph ? tin : xs;
    const short* Bh = ph ? qth : plth;
    const short* Bl = ph ? qtl : pltl;
    const short* bhb = Bh + (size_t)slab * 16384 + lane * 8;
    const short* blb = Bl + (size_t)slab * 16384 + lane * 8;

    // single B buffer: kc=0 loads issued BEFORE the staging barrier
    bf16x8 pbh[4], pbl[4];
    #pragma unroll
    for (int nf = 0; nf < 4; ++nf) {
      pbh[nf] = *reinterpret_cast<const bf16x8*>(bhb + nf * 512);
      pbl[nf] = *reinterpret_cast<const bf16x8*>(blb + nf * 512);
    }

    __syncthreads();
    #pragma unroll
    for (int i = 0; i < 32; ++i) {       // 32 coalesced 1KB wave-loads
      int idx4 = i * 64 + lane;
      int row = idx4 >> 6, col4 = idx4 & 63;
      float4 v = *reinterpret_cast<const float4*>(
          &A[(size_t)(mbase + row) * CS_ + k0 + col4 * 4]);
      *reinterpret_cast<float4*>(&at[row * 272 + col4 * 4]) = v;
    }
    __syncthreads();

    #pragma unroll
    for (int kc = 0; kc < 8; ++kc) {
      if (kc > 0) {                  // pb regs free after prev MFMAs
        #pragma unroll
        for (int nf = 0; nf < 4; ++nf) {
          pbh[nf] = *reinterpret_cast<const bf16x8*>(bhb + kc * 2048 + nf * 512);
          pbl[nf] = *reinterpret_cast<const bf16x8*>(blb + kc * 2048 + nf * 512);
        }
      }
      #pragma unroll
      for (int m2 = 0; m2 < 2; ++m2) {   // each B group feeds 24 MFMAs
        bf16x8 ah, al;
        {
          const float* ap = &at[(m2 * 16 + l15) * 272 + kc * 32 + kg * 8];
          float4 v0 = *reinterpret_cast<const float4*>(ap);
          float4 v1 = *reinterpret_cast<const float4*>(ap + 4);
          float f[8] = {v0.x, v0.y, v0.z, v0.w, v1.x, v1.y, v1.z, v1.w};
          #pragma unroll
          for (int jj = 0; jj < 8; ++jj) { short hh, ll; bsplit(f[jj], hh, ll); ah[jj] = hh; al[jj] = ll; }
        }
        #pragma unroll
        for (int nf = 0; nf < 4; ++nf) {
          acc[m2][nf] = __builtin_amdgcn_mfma_f32_16x16x32_bf16(ah, pbh[nf], acc[m2][nf], 0, 0, 0);
          acc[m2][nf] = __builtin_amdgcn_mfma_f32_16x16x32_bf16(ah, pbl[nf], acc[m2][nf], 0, 0, 0);
          acc[m2][nf] = __builtin_amdgcn_mfma_f32_16x16x32_bf16(al, pbh[nf], acc[m2][nf], 0, 0, 0);
        }
      }
    }
  }
  if (slab < 16) {                      // mur correction: 1 chunk per slab
    mf_chunk1<512, 512>(mur, pwth, pwtl, slab * 32, mbase,      l15, kg, acc[0]);
    mf_chunk1<512, 512>(mur, pwth, pwtl, slab * 32, mbase + 16, l15, kg, acc[1]);
  }

  // D layout: col = lane&15, row = (lane>>4)*4 + reg  [m89-verified]
  #pragma unroll
  for (int m2 = 0; m2 < 2; ++m2)
    #pragma unroll
    for (int nf = 0; nf < 4; ++nf)
      #pragma unroll
      for (int r = 0; r < 4; ++r) {
        int row = mbase + m2 * 16 + kg * 4 + r;
        int col = nf * 16 + l15;
        cwp2[(size_t)slab * 32768 + (size_t)row * 64 + col] = acc[m2][nf][r];
      }
}

// -------- 7. logits via MFMA (3-term split) + softmax + reweight + rn -------
__global__ void __launch_bounds__(256) k_logits(
    const float* __restrict__ x,
    const short* __restrict__ cwfh, const short* __restrict__ cwfm,
    const short* __restrict__ cwfl,
    const float* __restrict__ convb, const float* __restrict__ cwp2,
    const float* __restrict__ beta, const float* __restrict__ pb,
    float* __restrict__ wr, float* __restrict__ wsum) {
  __shared__ float sh[64 * 140];     // 35840 B: xt AND part2 (time-shared)
  __shared__ float sqp[4][49];
  __shared__ float cw4[4 * 49];
  __shared__ float mx4[4 * 49];
  __shared__ float sm4[4 * 49];
  float* xt = sh;
  float* part2 = sh;                 // [64][52] region, used after xt dies
  int n = blockIdx.x;
  int tid = threadIdx.x;
  int w = tid >> 6, lane = tid & 63;
  int l15 = lane & 15, kg = lane >> 4;
  float* pf = part2;
  const float* xb = x + (size_t)n * CS_;

  // zero wr pad cols s=49..63 (read as zeros by MFMA k_vssq/k_vout)
  for (int e = tid; e < 960; e += 256) {
    int kq = e / 15, p = e % 15;
    wr[((size_t)n * 64 + kq) * 64 + 49 + p] = 0.f;
  }
  // zero xt pad rows s=49..63 once (not clobbered until part2 phase)
  for (int e = tid; e < 1920; e += 256) {
    int row = 49 + e / 128, col = e % 128;
    xt[row * 140 + col] = 0.f;
  }

  // phase 0: cw slab reduction (98 slabs over 4 groups: 25/25/24/24)
  if (tid < 196) {
    int s = tid % 49, g = tid / 49;
    int st = (g < 2) ? g * 25 : 50 + (g - 2) * 24;
    int cnt = (g < 2) ? 25 : 24;
    const float* cp = cwp2 + (size_t)st * 32768 + (size_t)n * 64 + s;
    float a = 0.f;
    for (int i = 0; i < cnt; ++i) a += cp[(size_t)i * 32768];
    cw4[g * 49 + s] = a;
  }

  // phase 1: logits MFMA.  D[k=64][s=64pad] = sum_c convw[k][c] * x[c][s]
  int scol = tid % 49, sgrp = tid / 49;   // ssq mapping (tid < 196)
  float ssql = 0.f;
  f32x4 acc[4];
  #pragma unroll
  for (int nf = 0; nf < 4; ++nf) acc[nf] = (f32x4){0.f, 0.f, 0.f, 0.f};

  #pragma unroll 1
  for (int h = 0; h < 4; ++h) {
    int c0 = h * 128;
    __syncthreads();                 // xt safe to overwrite
    for (int e = tid; e < 6272; e += 256) {
      int c_row = e / 49, col = e % 49;
      xt[col * 140 + c_row] = xb[(size_t)c0 * 49 + e];
    }
    __syncthreads();

    if (tid < 196) {
      #pragma unroll 8
      for (int j = 0; j < 32; ++j) {
        float v = xt[scol * 140 + sgrp * 32 + j];
        ssql = fmaf(v, v, ssql);
      }
    }

    #pragma unroll
    for (int kcl = 0; kcl < 4; ++kcl) {
      int kc = h * 4 + kcl;
      bf16x8 ah = *reinterpret_cast<const bf16x8*>(cwfh + ((kc * 4 + w) * 64 + lane) * 8);
      bf16x8 am = *reinterpret_cast<const bf16x8*>(cwfm + ((kc * 4 + w) * 64 + lane) * 8);
      bf16x8 al = *reinterpret_cast<const bf16x8*>(cwfl + ((kc * 4 + w) * 64 + lane) * 8);
      #pragma unroll
      for (int nf = 0; nf < 4; ++nf) {
        const float* bp = &xt[(nf * 16 + l15) * 140 + kcl * 32 + kg * 8];
        float4 v0 = *reinterpret_cast<const float4*>(bp);
        float4 v1 = *reinterpret_cast<const float4*>(bp + 4);
        float f[8] = {v0.x, v0.y, v0.z, v0.w, v1.x, v1.y, v1.z, v1.w};
        bf16x8 bh, bm, bl;
        #pragma unroll
        for (int jj = 0; jj < 8; ++jj) {
          short hh, mm, ll; bsplit3(f[jj], hh, mm, ll);
          bh[jj] = hh; bm[jj] = mm; bl[jj] = ll;
        }
        acc[nf] = __builtin_amdgcn_mfma_f32_16x16x32_bf16(ah, bh, acc[nf], 0, 0, 0);
        acc[nf] = __builtin_amdgcn_mfma_f32_16x16x32_bf16(ah, bm, acc[nf], 0, 0, 0);
        acc[nf] = __builtin_amdgcn_mfma_f32_16x16x32_bf16(am, bh, acc[nf], 0, 0, 0);
        acc[nf] = __builtin_amdgcn_mfma_f32_16x16x32_bf16(ah, bl, acc[nf], 0, 0, 0);
        acc[nf] = __builtin_amdgcn_mfma_f32_16x16x32_bf16(am, bm, acc[nf], 0, 0, 0);
        acc[nf] = __builtin_amdgcn_mfma_f32_16x16x32_bf16(al, bh, acc[nf], 0, 0, 0);
      }
    }
  }
  __syncthreads();                   // ALL xt reads done; part2 (alias) next

  // D layout: s = nf*16 + l15, k = w*16 + kg*4 + r  [m89-verified]
  #pragma unroll
  for (int nf = 0; nf < 4; ++nf)
    #pragma unroll
    for (int r = 0; r < 4; ++r) {
      int s = nf * 16 + l15;
      if (s < 49) part2[(w * 16 + kg * 4 + r) * 52 + s] = acc[nf][r];
    }
  if (tid < 196) sqp[sgrp][scol] = ssql;
  __syncthreads();

  // phase 2: softmax over k, thread = (sg, s), 16 k's each
  float lg[16];
  int sg = tid / 49, s_ = tid % 49;
  float rnv = 0.f;
  if (tid < 196) {
    float sumsq = sqp[0][s_] + sqp[1][s_] + sqp[2][s_] + sqp[3][s_];
    rnv = 1.f / fmaxf(sqrtf(sumsq), 1e-12f);
    float mloc = -1e30f;
    #pragma unroll
    for (int kk = 0; kk < 16; ++kk) {
      int kq = sg * 16 + kk;
      lg[kk] = fmaf(part2[kq * 52 + s_], rnv, convb[kq]);
      mloc = fmaxf(mloc, lg[kk]);
    }
    mx4[sg * 49 + s_] = mloc;
  }
  __syncthreads();
  if (tid < 196) {
    float m0 = fmaxf(fmaxf(mx4[s_], mx4[49 + s_]), fmaxf(mx4[98 + s_], mx4[147 + s_]));
    float sloc = 0.f;
    #pragma unroll
    for (int kk = 0; kk < 16; ++kk) { lg[kk] = expf(lg[kk] - m0); sloc += lg[kk]; }
    sm4[sg * 49 + s_] = sloc;
  }
  __syncthreads();
  if (tid < 196) {
    float ssum = sm4[s_] + sm4[49 + s_] + sm4[98 + s_] + sm4[147 + s_];
    float cwv = cw4[s_] + cw4[49 + s_] + cw4[98 + s_] + cw4[147 + s_] + beta[0] + pb[s_];
    float inv = cwv / ssum;
    float wrs = inv * rnv;
    #pragma unroll
    for (int kk = 0; kk < 16; ++kk) {
      int kq = sg * 16 + kk;
      wr[((size_t)n * 64 + kq) * 64 + s_] = lg[kk] * wrs;
      pf[kq * 49 + s_] = lg[kk] * inv;
    }
  }
  __syncthreads();
  if (tid < 64) {
    float a = 0.f;
    #pragma unroll 7
    for (int s = 0; s < 49; ++s) a += pf[tid * 49 + s];
    wsum[n * 64 + tid] = a;
  }
}

// -------- 8a. VLAD ssq pass: MFMA, no store.  grid 1024 = (n, c-half) ------
__global__ void __launch_bounds__(256) k_vssq(
    const float* __restrict__ x, const float* __restrict__ wr,
    const float* __restrict__ wsum, const float* __restrict__ centT,
    float* __restrict__ ssqp2) {
  __shared__ float xt[128 * 68];     // 34816 B (no vl)
  __shared__ float sp[16][64];
  int n = blockIdx.x >> 1, ch = blockIdx.x & 1;
  int tid = threadIdx.x;
  int w = tid >> 6, lane = tid & 63;
  int l15 = lane & 15, kg = lane >> 4;
  const float* xb = x + (size_t)n * CS_;
  const float* wrb = wr + (size_t)n * 4096;
  const float* wsb = wsum + n * 64;

  // zero xt pad cols once (never clobbered — no vl here)
  for (int e = tid; e < 1920; e += 256) {
    int row = e / 15, col = 49 + e % 15;
    xt[row * 68 + col] = 0.f;
  }

  float wsk[4];
  #pragma unroll
  for (int nf = 0; nf < 4; ++nf) wsk[nf] = wsb[nf * 16 + l15];
  float ssqa[4] = {0.f, 0.f, 0.f, 0.f};

  #pragma unroll 1
  for (int hh = 0; hh < 2; ++hh) {
    int c0 = (ch * 2 + hh) * 128;
    __syncthreads();
    for (int e = tid; e < 6272; e += 256) {
      int row = e / 49, col = e % 49;
      xt[row * 68 + col] = xb[(size_t)c0 * 49 + e];
    }
    __syncthreads();

    f32x4 acc[2][4];
    #pragma unroll
    for (int mf = 0; mf < 2; ++mf)
      #pragma unroll
      for (int nf = 0; nf < 4; ++nf)
        acc[mf][nf] = (f32x4){0.f, 0.f, 0.f, 0.f};

    #pragma unroll
    for (int kc = 0; kc < 2; ++kc) {
      bf16x8 bh[4], bl[4];
      #pragma unroll
      for (int nf = 0; nf < 4; ++nf) {
        const float* bp = wrb + (nf * 16 + l15) * 64 + kc * 32 + kg * 8;
        float4 v0 = *reinterpret_cast<const float4*>(bp);
        float4 v1 = *reinterpret_cast<const float4*>(bp + 4);
        float f[8] = {v0.x, v0.y, v0.z, v0.w, v1.x, v1.y, v1.z, v1.w};
        #pragma unroll
        for (int jj = 0; jj < 8; ++jj) { short hh2, ll; bsplit(f[jj], hh2, ll); bh[nf][jj] = hh2; bl[nf][jj] = ll; }
      }
      #pragma unroll
      for (int mf = 0; mf < 2; ++mf) {
        bf16x8 ah, al;
        {
          const float* ap = &xt[(w * 32 + mf * 16 + l15) * 68 + kc * 32 + kg * 8];
          float4 v0 = *reinterpret_cast<const float4*>(ap);
          float4 v1 = *reinterpret_cast<const float4*>(ap + 4);
          float f[8] = {v0.x, v0.y, v0.z, v0.w, v1.x, v1.y, v1.z, v1.w};
          #pragma unroll
          for (int jj = 0; jj < 8; ++jj) { short hh2, ll; bsplit(f[jj], hh2, ll); ah[jj] = hh2; al[jj] = ll; }
        }
        #pragma unroll
        for (int nf = 0; nf < 4; ++nf) {
          acc[mf][nf] = __builtin_amdgcn_mfma_f32_16x16x32_bf16(ah, bh[nf], acc[mf][nf], 0, 0, 0);
          acc[mf][nf] = __builtin_amdgcn_mfma_f32_16x16x32_bf16(ah, bl[nf], acc[mf][nf], 0, 0, 0);
          acc[mf][nf] = __builtin_amdgcn_mfma_f32_16x16x32_bf16(al, bh[nf], acc[mf][nf], 0, 0, 0);
        }
      }
    }

    #pragma unroll
    for (int mf = 0; mf < 2; ++mf)
      #pragma unroll
      for (int nf = 0; nf < 4; ++nf)
        #pragma unroll
        for (int r = 0; r < 4; ++r) {
          int cc = w * 32 + mf * 16 + kg * 4 + r;
          int c = c0 + cc;
          int k = nf * 16 + l15;
          float v = fmaf(-centT[c * 64 + k], wsk[nf], acc[mf][nf][r]);
          ssqa[nf] = fmaf(v, v, ssqa[nf]);
        }
  }

  #pragma unroll
  for (int nf = 0; nf < 4; ++nf) sp[w * 4 + kg][nf * 16 + l15] = ssqa[nf];
  __syncthreads();
  if (tid < 64) {
    float v2 = 0.f;
    #pragma unroll
    for (int j = 0; j < 16; ++j) v2 += sp[j][tid];
    ssqp2[(size_t)(n * 2 + ch) * 64 + tid] = v2;
  }
}

// -------- 8b. VLAD out pass: recompute v, scal inline, single scaled write --
__global__ void __launch_bounds__(256) k_vout(
    const float* __restrict__ x, const float* __restrict__ wr,
    const float* __restrict__ wsum, const float* __restrict__ centT,
    const float* __restrict__ ssqp2, float* __restrict__ out) {
  __shared__ float sh[128 * 68];     // xt AND vl (time-shared)
  __shared__ float scal[64];
  float* xt = sh;
  float* vl = sh;                    // [64][129] region, written after xt dies
  int n = blockIdx.x >> 1, ch = blockIdx.x & 1;
  int tid = threadIdx.x;
  int w = tid >> 6, lane = tid & 63;
  int l15 = lane & 15, kg = lane >> 4;
  const float* xb = x + (size_t)n * CS_;
  const float* wrb = wr + (size_t)n * 4096;
  const float* wsb = wsum + n * 64;
  float* ob = out + (size_t)n * 32768;

  if (tid < 64) {                    // scal from partials (redundant per block)
    float v2 = ssqp2[(size_t)n * 128 + tid] + ssqp2[(size_t)n * 128 + 64 + tid];
    float vn = sqrtf(v2);
    float den = fmaxf(vn, 1e-12f);
    float cr = vn / den; cr *= cr;
    float g = wave_sum64(cr);
    scal[tid] = 1.f / (den * fmaxf(sqrtf(g), 1e-12f));
  }

  float wsk[4];
  #pragma unroll
  for (int nf = 0; nf < 4; ++nf) wsk[nf] = wsb[nf * 16 + l15];

  #pragma unroll 1
  for (int hh = 0; hh < 2; ++hh) {
    int c0 = (ch * 2 + hh) * 128;
    __syncthreads();                 // scal ready / prev vl drained
    for (int e = tid; e < 6272; e += 256) {
      int row = e / 49, col = e % 49;
      xt[row * 68 + col] = xb[(size_t)c0 * 49 + e];
    }
    for (int e = tid; e < 1920; e += 256) {   // re-zero pads (vl clobbers)
      int row = e / 15, col = 49 + e % 15;
      xt[row * 68 + col] = 0.f;
    }
    __syncthreads();

    f32x4 acc[2][4];
    #pragma unroll
    for (int mf = 0; mf < 2; ++mf)
      #pragma unroll
      for (int nf = 0; nf < 4; ++nf)
        acc[mf][nf] = (f32x4){0.f, 0.f, 0.f, 0.f};

    #pragma unroll
    for (int kc = 0; kc < 2; ++kc) {
      bf16x8 bh[4], bl[4];
      #pragma unroll
      for (int nf = 0; nf < 4; ++nf) {
        const float* bp = wrb + (nf * 16 + l15) * 64 + kc * 32 + kg * 8;
        float4 v0 = *reinterpret_cast<const float4*>(bp);
        float4 v1 = *reinterpret_cast<const float4*>(bp + 4);
        float f[8] = {v0.x, v0.y, v0.z, v0.w, v1.x, v1.y, v1.z, v1.w};
        #pragma unroll
        for (int jj = 0; jj < 8; ++jj) { short hh2, ll; bsplit(f[jj], hh2, ll); bh[nf][jj] = hh2; bl[nf][jj] = ll; }
      }
      #pragma unroll
      for (int mf = 0; mf < 2; ++mf) {
        bf16x8 ah, al;
        {
          const float* ap = &xt[(w * 32 + mf * 16 + l15) * 68 + kc * 32 + kg * 8];
          float4 v0 = *reinterpret_cast<const float4*>(ap);
          float4 v1 = *reinterpret_cast<const float4*>(ap + 4);
          float f[8] = {v0.x, v0.y, v0.z, v0.w, v1.x, v1.y, v1.z, v1.w};
          #pragma unroll
          for (int jj = 0; jj < 8; ++jj) { short hh2, ll; bsplit(f[jj], hh2, ll); ah[jj] = hh2; al[jj] = ll; }
        }
        #pragma unroll
        for (int nf = 0; nf < 4; ++nf) {
          acc[mf][nf] = __builtin_amdgcn_mfma_f32_16x16x32_bf16(ah, bh[nf], acc[mf][nf], 0, 0, 0);
          acc[mf][nf] = __builtin_amdgcn_mfma_f32_16x16x32_bf16(ah, bl[nf], acc[mf][nf], 0, 0, 0);
          acc[mf][nf] = __builtin_amdgcn_mfma_f32_16x16x32_bf16(al, bh[nf], acc[mf][nf], 0, 0, 0);
        }
      }
    }
    __syncthreads();                 // ALL xt reads done -> vl (alias) writable

    #pragma unroll
    for (int mf = 0; mf < 2; ++mf)
      #pragma unroll
      for (int nf = 0; nf < 4; ++nf)
        #pragma unroll
        for (int r = 0; r < 4; ++r) {
          int cc = w * 32 + mf * 16 + kg * 4 + r;
          int c = c0 + cc;
          int k = nf * 16 + l15;
          float v = fmaf(-centT[c * 64 + k], wsk[nf], acc[mf][nf][r]);
          vl[k * 129 + cc] = v * scal[k];
        }
    __syncthreads();
    #pragma unroll 4
    for (int e = tid; e < 8192; e += 256) {
      int k = e >> 7, cc = e & 127;
      ob[(size_t)k * 512 + c0 + cc] = vl[k * 129 + cc];   // single scaled write
    }
  }
}

extern "C" void kernel_launch(void* const* d_in, const int* in_sizes, int n_in,
                              void* d_out, int out_size, void* d_ws, size_t ws_size,
                              hipStream_t stream) {
  const float* x     = (const float*)d_in[0];
  const float* t     = (const float*)d_in[1];
  const float* cent  = (const float*)d_in[2];
  const float* convw = (const float*)d_in[3];
  const float* convb = (const float*)d_in[4];
  const float* lnw   = (const float*)d_in[5];
  const float* lnb   = (const float*)d_in[6];
  const float* w_t   = (const float*)d_in[7];
  const float* b_t   = (const float*)d_in[8];
  const float* w_s   = (const float*)d_in[9];
  const float* b_s   = (const float*)d_in[10];
  const float* w_m   = (const float*)d_in[11];
  const float* b_m   = (const float*)d_in[12];
  const float* w_l   = (const float*)d_in[13];
  const float* b_l   = (const float*)d_in[14];
  const float* accw  = (const float*)d_in[15];
  const float* accb  = (const float*)d_in[16];
  float* ws  = (float*)d_ws;
  float* out = (float*)d_out;

  float* wbs  = ws + OFF_WBS;
  float* wbm  = ws + OFF_WBM;
  float* wbl  = ws + OFF_WBL;
  float* wbt  = ws + OFF_WBT;
  float* beta = ws + OFF_BETA;
  short* cwfh = (short*)(ws + OFF_CWF);
  short* cwfm = (short*)(ws + OFF_CWF + 16384);
  short* cwfl = (short*)(ws + OFF_CWF + 32768);
  short* plth = (short*)(ws + OFF_PLTH);
  short* pltl = (short*)(ws + OFF_PLTL);
  short* qth  = (short*)(ws + OFF_QTH);
  short* qtl  = (short*)(ws + OFF_QTL);
  short* pwth = (short*)(ws + OFF_PWTH);
  short* pwtl = (short*)(ws + OFF_PWTL);
  float* PB   = ws + OFF_PB;
  float* pbp  = ws + OFF_PBP;
  float* mur  = ws + OFF_MUR;
  float* xs   = ws + OFF_XS;
  float* cwp2 = ws + OFF_CWP2;
  float* wr   = ws + OFF_WR;       // aliases xs (dead after k_cwg)
  float* wsumb = ws + OFF_WSUM;
  float* centT = ws + OFF_CENTT;
  float* ssqp2 = ws + OFF_SSQ2;

  k_wbar<<<dim3(406), dim3(256), 0, stream>>>(w_s, w_m, w_l, w_t, accw, accb,
                                              b_s, b_m, b_l, b_t,
                                              wbs, wbm, wbl, wbt, beta);
  k_wt<<<dim3(256), dim3(256), 0, stream>>>(convw, cent, cwfh, cwfm, cwfl, centT);
  k_xs<<<dim3(1024), dim3(256), 0, stream>>>(x, xs, mur);
  hipMemsetAsync(ws + OFF_PLTH, 0, (size_t)3244032 * 4, stream);  // pad rows q=49..63
  k_buildP<<<dim3(512), dim3(512), 0, stream>>>(wbs, wbm, wbl, wbt, lnw, lnb,
                                                plth, pltl, qth, qtl,
                                                pwth, pwtl, pbp);
  k_pb<<<dim3(49), dim3(64), 0, stream>>>(pbp, PB);
  k_cwg<<<dim3(1568), dim3(64), 0, stream>>>(xs, t, mur, plth, pltl, qth, qtl,
                                             pwth, pwtl, cwp2);
  k_logits<<<dim3(512), dim3(256), 0, stream>>>(x, cwfh, cwfm, cwfl, convb, cwp2,
                                                beta, PB, wr, wsumb);
  k_vssq<<<dim3(1024), dim3(256), 0, stream>>>(x, wr, wsumb, centT, ssqp2);
  k_vout<<<dim3(1024), dim3(256), 0, stream>>>(x, wr, wsumb, centT, ssqp2, out);
}

// Round 28
// 206.460 us; speedup vs baseline: 1.1754x; 1.1754x over previous
//
#include <hip/hip_runtime.h>
#include <cstdint>
#include <cstddef>

// ReweightVLAD on MI355X.  CRN collapsed to cw = xs·PLt − mur·PW + t·Qt + PB + β
// (LN folded: xs = x·rstd, PL = lnw·P).  All three big GEMMs on MFMA.
// Round 28: REVERT to the round-23 configuration (best measured: 212.6 µs).
// R24 (LDS aliasing), R25 (vlad split), R26 (single-buffer B), R27 (2-mtile)
// all regressed (223/220/225/243).  This is a bit-identical resubmission of
// the round-23 source.

#define N_   512
#define C_   512
#define S_   49
#define CS_  25088   // C_*S_

// ---- ws layout (float offsets) ----
#define OFF_WBS   0u
#define OFF_WBM   4608u
#define OFF_WBL   29696u
#define OFF_WBT   71168u
#define OFF_BETA  103936u
// [103952, 136720) free
#define OFF_PLTH  136720u      // bf16 fragment-packed [98 slab][8 kc][4 nf][64 lane][8]
#define OFF_PLTL  939536u      // = 1605632 shorts = 802816 fl each
#define OFF_QTH   1742352u
#define OFF_QTL   2545168u
#define OFF_PWTH  3347984u     // bf16 [64][512] = 16384 fl each (stores -PW)
#define OFF_PWTL  3364368u
// memset region [OFF_PLTH, 3380752) = 3244032 floats
#define OFF_PB    3380752u     // 64
#define OFF_PBP   3380816u     // 25088  [q][c]
#define OFF_MUR   3405904u     // 262144 fp32 [n][c]
#define OFF_XS    3668048u     // 12845056 fp32 [n][cs]
#define OFF_WR    3668048u     // aliases XS (dead after k_cwg); 512*64*64
#define OFF_CWP2  16513104u    // 98*512*64 = 3211264 fp32
#define OFF_WSUM  19724368u    // 32768
#define OFF_CENTT 19757136u    // 32768 fp32 centT[c][64]
#define OFF_CWF   19789904u    // 3-way split conv_w: h/m/l, 16384 fl EACH
// total = 19839056 floats ≈ 79.4 MB

typedef __attribute__((ext_vector_type(8))) short bf16x8;
typedef __attribute__((ext_vector_type(4))) float f32x4;

__device__ __forceinline__ float wave_sum64(float v) {
  #pragma unroll
  for (int off = 32; off; off >>= 1) v += __shfl_xor(v, off, 64);
  return v;
}

__device__ __forceinline__ void bsplit(float f, short& h, short& l) {
  unsigned u = __float_as_uint(f);
  h = (short)(u >> 16);
  float hf = __uint_as_float(u & 0xffff0000u);
  l = (short)(__float_as_uint(f - hf) >> 16);
}

__device__ __forceinline__ void bsplit3(float f, short& h, short& m, short& l) {
  unsigned u = __float_as_uint(f);
  h = (short)(u >> 16);
  float hf = __uint_as_float(u & 0xffff0000u);
  float r1 = f - hf;
  unsigned u1 = __float_as_uint(r1);
  m = (short)(u1 >> 16);
  float mf = __uint_as_float(u1 & 0xffff0000u);
  float r2 = r1 - mf;
  l = (short)(__float_as_uint(r2) >> 16);
}

// bilinear align_corners 7->20 matrix entry
__device__ __forceinline__ float m20val(int r, int p) {
  float pos = (float)(r * 6) / 19.0f;
  int lo = (int)floorf(pos);
  int hi = min(lo + 1, 6);
  float fr = pos - (float)lo;
  float v = 0.f;
  if (p == lo) v += 1.f - fr;
  if (p == hi) v += fr;
  return v;
}

// -------- 1. fold acc_w into conv weights; beta scalar --------
__global__ void k_wbar(const float* __restrict__ w_s, const float* __restrict__ w_m,
                       const float* __restrict__ w_l, const float* __restrict__ w_t,
                       const float* __restrict__ accw, const float* __restrict__ accb,
                       const float* __restrict__ b_s, const float* __restrict__ b_m,
                       const float* __restrict__ b_l, const float* __restrict__ b_t,
                       float* __restrict__ wbs, float* __restrict__ wbm,
                       float* __restrict__ wbl, float* __restrict__ wbt,
                       float* __restrict__ beta) {
  int id = blockIdx.x * 256 + threadIdx.x;      // [0, 103936) exact
  if (id == 0) {
    float b = accb[0];
    for (int o = 0; o < 32; ++o) b = fmaf(accw[o],      b_s[o], b);
    for (int o = 0; o < 32; ++o) b = fmaf(accw[32 + o], b_m[o], b);
    for (int o = 0; o < 20; ++o) b = fmaf(accw[64 + o], b_l[o], b);
    for (int o = 0; o < 16; ++o) b = fmaf(accw[84 + o], b_t[o], b);
    beta[0] = b;
  }
  if (id < 4608) {
    int c = id / 9, uv = id % 9;
    float a = 0.f;
    for (int o = 0; o < 32; ++o) a = fmaf(accw[o], w_s[(size_t)(o * 512 + c) * 9 + uv], a);
    wbs[id] = a;
  } else if (id < 29696) {
    int i2 = id - 4608; int c = i2 / 49, uv = i2 % 49;
    float a = 0.f;
    for (int o = 0; o < 32; ++o) a = fmaf(accw[32 + o], w_m[(size_t)(o * 512 + c) * 49 + uv], a);
    wbm[i2] = a;
  } else if (id < 71168) {
    int i2 = id - 29696; int c = i2 / 81, uv = i2 % 81;
    float a = 0.f;
    for (int o = 0; o < 20; ++o) a = fmaf(accw[64 + o], w_l[(size_t)(o * 512 + c) * 81 + uv], a);
    wbl[i2] = a;
  } else {
    int i2 = id - 71168; int c = i2 / 64, uv = i2 % 64;
    float a = 0.f;
    for (int o = 0; o < 16; ++o) a = fmaf(accw[84 + o], w_t[(size_t)(o * 512 + c) * 64 + uv], a);
    wbt[i2] = a;
  }
}

// -------- 2. conv_w -> 3-way split + fragment-packed; cent -> centT --------
// element (k,c): kc=c>>5, kg=(c>>3)&3, off=c&7, w=k>>4, l15=k&15
// idx = ((kc*4 + w)*64 + kg*16 + l15)*8 + off  -> wave A-load = 1KB contiguous
__global__ void k_wt(const float* __restrict__ convw, const float* __restrict__ cent,
                     short* __restrict__ cwfh, short* __restrict__ cwfm,
                     short* __restrict__ cwfl, float* __restrict__ centT) {
  int id = blockIdx.x * 256 + threadIdx.x;   // [0, 65536)
  if (id < 32768) {
    int k = id >> 9, c = id & 511;
    short h, m, l; bsplit3(convw[(size_t)k * 512 + c], h, m, l);
    int kc = c >> 5, kg = (c >> 3) & 3, off = c & 7;
    int w = k >> 4, l15 = k & 15;
    int idx = ((kc * 4 + w) * 64 + kg * 16 + l15) * 8 + off;
    cwfh[idx] = h; cwfm[idx] = m; cwfl[idx] = l;
  } else {
    int id2 = id - 32768;
    int k = id2 & 63, c = id2 >> 6;
    centT[id2] = cent[(size_t)k * 512 + c];
  }
}

// -------- 3. LN stats + scaled copy: xs = x*rstd, mur = mu*rstd --------
__global__ void k_xs(const float* __restrict__ x, float* __restrict__ xs,
                     float* __restrict__ mur) {
  int idx = blockIdx.x * 256 + threadIdx.x;     // [0, 262144) = (n,c)
  const float* p = x + (size_t)idx * 49;
  float s1 = 0.f, s2 = 0.f;
  #pragma unroll
  for (int s = 0; s < 49; ++s) { float v = p[s]; s1 += v; s2 = fmaf(v, v, s2); }
  float m = s1 * (1.f / 49.f);
  float var = s2 * (1.f / 49.f) - m * m;
  float r = 1.f / sqrtf(var + 1e-5f);
  float* o = xs + (size_t)idx * 49;
  #pragma unroll
  for (int s = 0; s < 49; ++s) o[s] = p[s] * r;
  mur[idx] = m * r;
}

// -------- 4. buildP: block=c, LDS tile, fragment-packed B output,
//            fused PW/PB fold --------
__global__ void __launch_bounds__(512) k_buildP(
    const float* __restrict__ wbs, const float* __restrict__ wbm,
    const float* __restrict__ wbl, const float* __restrict__ wbt,
    const float* __restrict__ lnw, const float* __restrict__ lnb,
    short* __restrict__ plth, short* __restrict__ pltl,
    short* __restrict__ qth,  short* __restrict__ qtl,
    short* __restrict__ pwth, short* __restrict__ pwtl,
    float* __restrict__ pbp) {
  __shared__ float M[20][7];
  __shared__ float tP[49][50];
  __shared__ float tQ[49][50];
  int c = blockIdx.x;
  int tid = threadIdx.x;
  if (tid < 140) { int r = tid / 7, p = tid % 7; M[r][p] = m20val(r, p); }
  __syncthreads();

  const float* wbsr = wbs + c * 9;     // block-uniform -> s_load feed
  const float* wbmr = wbm + c * 49;
  const float* wblr = wbl + c * 81;
  const float* wbtr = wbt + c * 64;

  // compute tile: e = s*49 + q
  for (int e = tid; e < 2401; e += 512) {
    int s = e / 49, q = e % 49;
    int i = q / 7, j = q % 7, pp = s / 7, qq = s % 7;

    float sumP = 0.f;
    { // xs: 3x3, stride 3, pad 1
      float rv[3];
      #pragma unroll
      for (int v = 0; v < 3; ++v) { int col = j * 3 - 1 + v; rv[v] = ((unsigned)col < 20u) ? M[col][qq] : 0.f; }
      #pragma unroll
      for (int u = 0; u < 3; ++u) {
        int row = i * 3 - 1 + u; float ru = ((unsigned)row < 20u) ? M[row][pp] : 0.f;
        float a = wbsr[u * 3 + 0] * rv[0];
        a = fmaf(wbsr[u * 3 + 1], rv[1], a);
        a = fmaf(wbsr[u * 3 + 2], rv[2], a);
        sumP = fmaf(ru, a, sumP);
      }
    }
    { // xm: 7x7, stride 5, pad 9
      float rv[7];
      #pragma unroll
      for (int v = 0; v < 7; ++v) { int col = j * 5 - 9 + v; rv[v] = ((unsigned)col < 20u) ? M[col][qq] : 0.f; }
      #pragma unroll
      for (int u = 0; u < 7; ++u) {
        int row = i * 5 - 9 + u; float ru = ((unsigned)row < 20u) ? M[row][pp] : 0.f;
        float a = 0.f;
        #pragma unroll
        for (int v = 0; v < 7; ++v) a = fmaf(wbmr[u * 7 + v], rv[v], a);
        sumP = fmaf(ru, a, sumP);
      }
    }
    { // xl: 9x9, stride 2, pad 1
      float rv[9];
      #pragma unroll
      for (int v = 0; v < 9; ++v) { int col = j * 2 - 1 + v; rv[v] = ((unsigned)col < 20u) ? M[col][qq] : 0.f; }
      #pragma unroll
      for (int u = 0; u < 9; ++u) {
        int row = i * 2 - 1 + u; float ru = ((unsigned)row < 20u) ? M[row][pp] : 0.f;
        float a = 0.f;
        #pragma unroll
        for (int v = 0; v < 9; ++v) a = fmaf(wblr[u * 9 + v], rv[v], a);
        sumP = fmaf(ru, a, sumP);
      }
    }
    tP[s][q] = sumP;

    float sumQ = 0.f;
    { // tc: 8x8, stride 2, pad 0
      float rv[8];
      #pragma unroll
      for (int v = 0; v < 8; ++v) { int col = j * 2 + v; rv[v] = ((unsigned)col < 20u) ? M[col][qq] : 0.f; }
      #pragma unroll
      for (int u = 0; u < 8; ++u) {
        int row = i * 2 + u; float ru = ((unsigned)row < 20u) ? M[row][pp] : 0.f;
        float a = 0.f;
        #pragma unroll
        for (int v = 0; v < 8; ++v) a = fmaf(wbtr[u * 8 + v], rv[v], a);
        sumQ = fmaf(ru, a, sumQ);
      }
    }
    tQ[s][q] = sumQ;
  }
  __syncthreads();

  // transpose-out in MFMA fragment-packed order:
  for (int e = tid; e < 2401; e += 512) {
    int q = e / 49, s = e % 49;
    float pv = tP[s][q];
    float qv = tQ[s][q];
    int k = c * 49 + s;
    int slab = k >> 8;
    int kc = (k & 255) >> 5;
    int kg = (k >> 3) & 3;
    int off = k & 7;
    int nf = q >> 4, l15 = q & 15;
    size_t oidx = (size_t)slab * 16384 + kc * 2048 + nf * 512
                + (size_t)(kg * 16 + l15) * 8 + off;
    short h, l;
    bsplit(lnw[s] * pv, h, l); plth[oidx] = h; pltl[oidx] = l;
    bsplit(qv, h, l);          qth[oidx]  = h; qtl[oidx]  = l;
  }

  // fused fold: pw[q] = sum_s lnw*P, pb[q] = sum_s lnb*P
  if (tid < 49) {
    int q = tid;
    float pw = 0.f, pb = 0.f;
    #pragma unroll 7
    for (int s = 0; s < 49; ++s) {
      float p = tP[s][q];
      pw = fmaf(lnw[s], p, pw);
      pb = fmaf(lnb[s], p, pb);
    }
    short h, l; bsplit(-pw, h, l);
    pwth[q * 512 + c] = h;
    pwtl[q * 512 + c] = l;
    pbp[q * 512 + c] = pb;
  }
}

// -------- 5. PB[q] = sum_c PBp[q][c] --------
__global__ void k_pb(const float* __restrict__ pbp, float* __restrict__ PB) {
  int q = blockIdx.x, lane = threadIdx.x;   // grid 49 x 64
  float a = 0.f;
  for (int c = lane; c < 512; c += 64) a += pbp[q * 512 + c];
  a = wave_sum64(a);
  if (lane == 0) PB[q] = a;
}

// -------- 6. MFMA split-bf16 GEMM: cwp2[slab][n][64], pipelined B feed ------
template <int SA, int SB>
__device__ __forceinline__ void mf_chunk1(const float* __restrict__ A,
                                          const short* __restrict__ Bh,
                                          const short* __restrict__ Bl,
                                          int k, int mbase, int l15, int kg,
                                          f32x4 (&acc)[4]) {
  bf16x8 ah, al;
  {
    const float* ap = A + (size_t)(mbase + l15) * SA + k + kg * 8;
    float4 v0 = *reinterpret_cast<const float4*>(ap);
    float4 v1 = *reinterpret_cast<const float4*>(ap + 4);
    float f[8] = {v0.x, v0.y, v0.z, v0.w, v1.x, v1.y, v1.z, v1.w};
    #pragma unroll
    for (int jj = 0; jj < 8; ++jj) { short hh, ll; bsplit(f[jj], hh, ll); ah[jj] = hh; al[jj] = ll; }
  }
  #pragma unroll
  for (int nf = 0; nf < 4; ++nf) {
    size_t bo = (size_t)(nf * 16 + l15) * SB + k + kg * 8;
    bf16x8 bh = *reinterpret_cast<const bf16x8*>(Bh + bo);
    bf16x8 bl = *reinterpret_cast<const bf16x8*>(Bl + bo);
    acc[nf] = __builtin_amdgcn_mfma_f32_16x16x32_bf16(ah, bh, acc[nf], 0, 0, 0);
    acc[nf] = __builtin_amdgcn_mfma_f32_16x16x32_bf16(ah, bl, acc[nf], 0, 0, 0);
    acc[nf] = __builtin_amdgcn_mfma_f32_16x16x32_bf16(al, bh, acc[nf], 0, 0, 0);
  }
}

__global__ void __launch_bounds__(64) k_cwg(
    const float* __restrict__ xs, const float* __restrict__ tin,
    const float* __restrict__ mur,
    const short* __restrict__ plth, const short* __restrict__ pltl,
    const short* __restrict__ qth,  const short* __restrict__ qtl,
    const short* __restrict__ pwth, const short* __restrict__ pwtl,
    float* __restrict__ cwp2) {
  __shared__ float at[16 * 272];       // stride 272: 2-way banks (free)
  int wgid = (blockIdx.x & 7) * 392 + (blockIdx.x >> 3);
  int slab = wgid >> 5, mt = wgid & 31;  // 98 slabs x 32 m-tiles of 16 rows
  int lane = threadIdx.x;
  int l15 = lane & 15, kg = lane >> 4;
  int mbase = mt * 16;
  int k0 = slab * 256;

  f32x4 acc[4];
  #pragma unroll
  for (int nf = 0; nf < 4; ++nf) acc[nf] = (f32x4){0.f, 0.f, 0.f, 0.f};

  #pragma unroll 1
  for (int ph = 0; ph < 2; ++ph) {
    const float* A  = ph ? tin : xs;
    const short* Bh = ph ? qth : plth;
    const short* Bl = ph ? qtl : pltl;
    const short* bhb = Bh + (size_t)slab * 16384 + lane * 8;
    const short* blb = Bl + (size_t)slab * 16384 + lane * 8;

    bf16x8 pbh[2][4], pbl[2][4];
    #pragma unroll
    for (int nf = 0; nf < 4; ++nf) {
      pbh[0][nf] = *reinterpret_cast<const bf16x8*>(bhb + nf * 512);
      pbl[0][nf] = *reinterpret_cast<const bf16x8*>(blb + nf * 512);
    }

    __syncthreads();
    #pragma unroll
    for (int i = 0; i < 16; ++i) {
      int idx4 = i * 64 + lane;
      int row = idx4 >> 6, col4 = idx4 & 63;
      float4 v = *reinterpret_cast<const float4*>(
          &A[(size_t)(mbase + row) * CS_ + k0 + col4 * 4]);
      *reinterpret_cast<float4*>(&at[row * 272 + col4 * 4]) = v;
    }
    __syncthreads();

    #pragma unroll
    for (int kc = 0; kc < 8; ++kc) {
      int cur = kc & 1, nxt = cur ^ 1;
      if (kc < 7) {
        #pragma unroll
        for (int nf = 0; nf < 4; ++nf) {
          pbh[nxt][nf] = *reinterpret_cast<const bf16x8*>(bhb + (kc + 1) * 2048 + nf * 512);
          pbl[nxt][nf] = *reinterpret_cast<const bf16x8*>(blb + (kc + 1) * 2048 + nf * 512);
        }
      }
      bf16x8 ah, al;
      {
        const float* ap = &at[l15 * 272 + kc * 32 + kg * 8];
        float4 v0 = *reinterpret_cast<const float4*>(ap);
        float4 v1 = *reinterpret_cast<const float4*>(ap + 4);
        float f[8] = {v0.x, v0.y, v0.z, v0.w, v1.x, v1.y, v1.z, v1.w};
        #pragma unroll
        for (int jj = 0; jj < 8; ++jj) { short hh, ll; bsplit(f[jj], hh, ll); ah[jj] = hh; al[jj] = ll; }
      }
      #pragma unroll
      for (int nf = 0; nf < 4; ++nf) {
        acc[nf] = __builtin_amdgcn_mfma_f32_16x16x32_bf16(ah, pbh[cur][nf], acc[nf], 0, 0, 0);
        acc[nf] = __builtin_amdgcn_mfma_f32_16x16x32_bf16(ah, pbl[cur][nf], acc[nf], 0, 0, 0);
        acc[nf] = __builtin_amdgcn_mfma_f32_16x16x32_bf16(al, pbh[cur][nf], acc[nf], 0, 0, 0);
      }
    }
  }
  if (slab < 16)
    mf_chunk1<512, 512>(mur, pwth, pwtl, slab * 32, mbase, l15, kg, acc);

  #pragma unroll
  for (int nf = 0; nf < 4; ++nf)
    #pragma unroll
    for (int r = 0; r < 4; ++r) {
      int row = mbase + kg * 4 + r;
      int col = nf * 16 + l15;
      cwp2[(size_t)slab * 32768 + (size_t)row * 64 + col] = acc[nf][r];
    }
}

// -------- 7. logits via MFMA (3-term split) + softmax + reweight + rn -------
__global__ void __launch_bounds__(256) k_logits(
    const float* __restrict__ x,
    const short* __restrict__ cwfh, const short* __restrict__ cwfm,
    const short* __restrict__ cwfl,
    const float* __restrict__ convb, const float* __restrict__ cwp2,
    const float* __restrict__ beta, const float* __restrict__ pb,
    float* __restrict__ wr, float* __restrict__ wsum) {
  __shared__ float xt[64 * 140];     // 35840 B: xT[s pad 64][c-chunk 128]
  __shared__ float part2[64 * 52];   // 13312 B: logits[k][s]; reused for wsum
  __shared__ float sqp[4][49];
  __shared__ float cw4[4 * 49];
  __shared__ float mx4[4 * 49];
  __shared__ float sm4[4 * 49];
  int n = blockIdx.x;
  int tid = threadIdx.x;
  int w = tid >> 6, lane = tid & 63;
  int l15 = lane & 15, kg = lane >> 4;
  float* pf = part2;
  const float* xb = x + (size_t)n * CS_;

  // zero wr pad cols s=49..63 (read as zeros by MFMA k_vlad)
  for (int e = tid; e < 960; e += 256) {
    int kq = e / 15, p = e % 15;
    wr[((size_t)n * 64 + kq) * 64 + 49 + p] = 0.f;
  }
  // zero xt pad rows s=49..63 once (never written by staging)
  for (int e = tid; e < 1920; e += 256) {
    int row = 49 + e / 128, col = e % 128;
    xt[row * 140 + col] = 0.f;
  }

  // phase 0: cw slab reduction (98 slabs over 4 groups: 25/25/24/24)
  if (tid < 196) {
    int s = tid % 49, g = tid / 49;
    int st = (g < 2) ? g * 25 : 50 + (g - 2) * 24;
    int cnt = (g < 2) ? 25 : 24;
    const float* cp = cwp2 + (size_t)st * 32768 + (size_t)n * 64 + s;
    float a = 0.f;
    for (int i = 0; i < cnt; ++i) a += cp[(size_t)i * 32768];
    cw4[g * 49 + s] = a;
  }

  // phase 1: logits MFMA.  D[k=64][s=64pad] = sum_c convw[k][c] * x[c][s]
  int scol = tid % 49, sgrp = tid / 49;   // ssq mapping (tid < 196)
  float ssql = 0.f;
  f32x4 acc[4];
  #pragma unroll
  for (int nf = 0; nf < 4; ++nf) acc[nf] = (f32x4){0.f, 0.f, 0.f, 0.f};

  #pragma unroll 1
  for (int h = 0; h < 4; ++h) {
    int c0 = h * 128;
    __syncthreads();                 // xt safe to overwrite
    for (int e = tid; e < 6272; e += 256) {
      int c_row = e / 49, col = e % 49;
      xt[col * 140 + c_row] = xb[(size_t)c0 * 49 + e];
    }
    __syncthreads();

    if (tid < 196) {
      #pragma unroll 8
      for (int j = 0; j < 32; ++j) {
        float v = xt[scol * 140 + sgrp * 32 + j];
        ssql = fmaf(v, v, ssql);
      }
    }

    #pragma unroll
    for (int kcl = 0; kcl < 4; ++kcl) {
      int kc = h * 4 + kcl;
      bf16x8 ah = *reinterpret_cast<const bf16x8*>(cwfh + ((kc * 4 + w) * 64 + lane) * 8);
      bf16x8 am = *reinterpret_cast<const bf16x8*>(cwfm + ((kc * 4 + w) * 64 + lane) * 8);
      bf16x8 al = *reinterpret_cast<const bf16x8*>(cwfl + ((kc * 4 + w) * 64 + lane) * 8);
      #pragma unroll
      for (int nf = 0; nf < 4; ++nf) {
        const float* bp = &xt[(nf * 16 + l15) * 140 + kcl * 32 + kg * 8];
        float4 v0 = *reinterpret_cast<const float4*>(bp);
        float4 v1 = *reinterpret_cast<const float4*>(bp + 4);
        float f[8] = {v0.x, v0.y, v0.z, v0.w, v1.x, v1.y, v1.z, v1.w};
        bf16x8 bh, bm, bl;
        #pragma unroll
        for (int jj = 0; jj < 8; ++jj) {
          short hh, mm, ll; bsplit3(f[jj], hh, mm, ll);
          bh[jj] = hh; bm[jj] = mm; bl[jj] = ll;
        }
        // 6-term product: error ~2^-24 relative
        acc[nf] = __builtin_amdgcn_mfma_f32_16x16x32_bf16(ah, bh, acc[nf], 0, 0, 0);
        acc[nf] = __builtin_amdgcn_mfma_f32_16x16x32_bf16(ah, bm, acc[nf], 0, 0, 0);
        acc[nf] = __builtin_amdgcn_mfma_f32_16x16x32_bf16(am, bh, acc[nf], 0, 0, 0);
        acc[nf] = __builtin_amdgcn_mfma_f32_16x16x32_bf16(ah, bl, acc[nf], 0, 0, 0);
        acc[nf] = __builtin_amdgcn_mfma_f32_16x16x32_bf16(am, bm, acc[nf], 0, 0, 0);
        acc[nf] = __builtin_amdgcn_mfma_f32_16x16x32_bf16(al, bh, acc[nf], 0, 0, 0);
      }
    }
  }
  __syncthreads();                   // xt reads done; part2/sqp writes next

  // D layout: s = nf*16 + l15, k = w*16 + kg*4 + r  [m89-verified]
  #pragma unroll
  for (int nf = 0; nf < 4; ++nf)
    #pragma unroll
    for (int r = 0; r < 4; ++r) {
      int s = nf * 16 + l15;
      if (s < 49) part2[(w * 16 + kg * 4 + r) * 52 + s] = acc[nf][r];
    }
  if (tid < 196) sqp[sgrp][scol] = ssql;
  __syncthreads();

  // phase 2: softmax over k, thread = (sg, s), 16 k's each
  float lg[16];
  int sg = tid / 49, s_ = tid % 49;
  float rnv = 0.f;
  if (tid < 196) {
    float sumsq = sqp[0][s_] + sqp[1][s_] + sqp[2][s_] + sqp[3][s_];
    rnv = 1.f / fmaxf(sqrtf(sumsq), 1e-12f);
    float mloc = -1e30f;
    #pragma unroll
    for (int kk = 0; kk < 16; ++kk) {
      int kq = sg * 16 + kk;
      lg[kk] = fmaf(part2[kq * 52 + s_], rnv, convb[kq]);
      mloc = fmaxf(mloc, lg[kk]);
    }
    mx4[sg * 49 + s_] = mloc;
  }
  __syncthreads();
  if (tid < 196) {
    float m0 = fmaxf(fmaxf(mx4[s_], mx4[49 + s_]), fmaxf(mx4[98 + s_], mx4[147 + s_]));
    float sloc = 0.f;
    #pragma unroll
    for (int kk = 0; kk < 16; ++kk) { lg[kk] = expf(lg[kk] - m0); sloc += lg[kk]; }
    sm4[sg * 49 + s_] = sloc;
  }
  __syncthreads();
  if (tid < 196) {
    float ssum = sm4[s_] + sm4[49 + s_] + sm4[98 + s_] + sm4[147 + s_];
    float cwv = cw4[s_] + cw4[49 + s_] + cw4[98 + s_] + cw4[147 + s_] + beta[0] + pb[s_];
    float inv = cwv / ssum;
    float wrs = inv * rnv;
    #pragma unroll
    for (int kk = 0; kk < 16; ++kk) {
      int kq = sg * 16 + kk;
      wr[((size_t)n * 64 + kq) * 64 + s_] = lg[kk] * wrs;
      pf[kq * 49 + s_] = lg[kk] * inv;
    }
  }
  __syncthreads();
  if (tid < 64) {
    float a = 0.f;
    #pragma unroll 7
    for (int s = 0; s < 49; ++s) a += pf[tid * 49 + s];
    wsum[n * 64 + tid] = a;
  }
}

// -------- 8. VLAD via MFMA: per n, D[c=512,k=64] = x·wr^T (split-bf16) ------
__global__ void __launch_bounds__(256) k_vlad(
    const float* __restrict__ x, const float* __restrict__ wr,
    const float* __restrict__ wsum, const float* __restrict__ centT,
    float* __restrict__ out) {
  __shared__ float xt[128 * 68];     // 34816 B
  __shared__ float vl[64 * 129];     // 33024 B
  __shared__ float sp[16][64];
  __shared__ float scal[64];
  int n = blockIdx.x;
  int tid = threadIdx.x;
  int w = tid >> 6, lane = tid & 63;
  int l15 = lane & 15, kg = lane >> 4;
  const float* xb = x + (size_t)n * CS_;
  const float* wrb = wr + (size_t)n * 4096;
  const float* wsb = wsum + n * 64;
  float* ob = out + (size_t)n * 32768;

  // zero xt pad cols 49..63 once (never overwritten by staging)
  for (int e = tid; e < 1920; e += 256) {
    int row = e / 15, col = 49 + e % 15;
    xt[row * 68 + col] = 0.f;
  }

  float wsk[4];
  #pragma unroll
  for (int nf = 0; nf < 4; ++nf) wsk[nf] = wsb[nf * 16 + l15];
  float ssqa[4] = {0.f, 0.f, 0.f, 0.f};

  #pragma unroll 1
  for (int h = 0; h < 4; ++h) {
    int c0 = h * 128;
    __syncthreads();
    for (int e = tid; e < 6272; e += 256) {
      int row = e / 49, col = e % 49;
      xt[row * 68 + col] = xb[(size_t)c0 * 49 + e];
    }
    __syncthreads();

    f32x4 acc[2][4];
    #pragma unroll
    for (int mf = 0; mf < 2; ++mf)
      #pragma unroll
      for (int nf = 0; nf < 4; ++nf)
        acc[mf][nf] = (f32x4){0.f, 0.f, 0.f, 0.f};

    #pragma unroll
    for (int kc = 0; kc < 2; ++kc) {
      bf16x8 bh[4], bl[4];
      #pragma unroll
      for (int nf = 0; nf < 4; ++nf) {
        const float* bp = wrb + (nf * 16 + l15) * 64 + kc * 32 + kg * 8;
        float4 v0 = *reinterpret_cast<const float4*>(bp);
        float4 v1 = *reinterpret_cast<const float4*>(bp + 4);
        float f[8] = {v0.x, v0.y, v0.z, v0.w, v1.x, v1.y, v1.z, v1.w};
        #pragma unroll
        for (int jj = 0; jj < 8; ++jj) { short hh, ll; bsplit(f[jj], hh, ll); bh[nf][jj] = hh; bl[nf][jj] = ll; }
      }
      #pragma unroll
      for (int mf = 0; mf < 2; ++mf) {
        bf16x8 ah, al;
        {
          const float* ap = &xt[(w * 32 + mf * 16 + l15) * 68 + kc * 32 + kg * 8];
          float4 v0 = *reinterpret_cast<const float4*>(ap);
          float4 v1 = *reinterpret_cast<const float4*>(ap + 4);
          float f[8] = {v0.x, v0.y, v0.z, v0.w, v1.x, v1.y, v1.z, v1.w};
          #pragma unroll
          for (int jj = 0; jj < 8; ++jj) { short hh, ll; bsplit(f[jj], hh, ll); ah[jj] = hh; al[jj] = ll; }
        }
        #pragma unroll
        for (int nf = 0; nf < 4; ++nf) {
          acc[mf][nf] = __builtin_amdgcn_mfma_f32_16x16x32_bf16(ah, bh[nf], acc[mf][nf], 0, 0, 0);
          acc[mf][nf] = __builtin_amdgcn_mfma_f32_16x16x32_bf16(ah, bl[nf], acc[mf][nf], 0, 0, 0);
          acc[mf][nf] = __builtin_amdgcn_mfma_f32_16x16x32_bf16(al, bh[nf], acc[mf][nf], 0, 0, 0);
        }
      }
    }

    #pragma unroll
    for (int mf = 0; mf < 2; ++mf)
      #pragma unroll
      for (int nf = 0; nf < 4; ++nf)
        #pragma unroll
        for (int r = 0; r < 4; ++r) {
          int cc = w * 32 + mf * 16 + kg * 4 + r;
          int c = c0 + cc;
          int k = nf * 16 + l15;
          float v = fmaf(-centT[c * 64 + k], wsk[nf], acc[mf][nf][r]);
          vl[k * 129 + cc] = v;
          ssqa[nf] = fmaf(v, v, ssqa[nf]);
        }
    __syncthreads();
    #pragma unroll 4
    for (int e = tid; e < 8192; e += 256) {
      int k = e >> 7, cc = e & 127;
      ob[(size_t)k * 512 + c0 + cc] = vl[k * 129 + cc];
    }
  }

  #pragma unroll
  for (int nf = 0; nf < 4; ++nf) sp[w * 4 + kg][nf * 16 + l15] = ssqa[nf];
  __syncthreads();
  if (tid < 64) {
    float v2 = 0.f;
    #pragma unroll
    for (int j = 0; j < 16; ++j) v2 += sp[j][tid];
    float vn = sqrtf(v2);
    float den = fmaxf(vn, 1e-12f);
    float cr = vn / den; cr *= cr;
    float g = wave_sum64(cr);
    scal[tid] = 1.f / (den * fmaxf(sqrtf(g), 1e-12f));
  }
  __syncthreads();
  #pragma unroll 8
  for (int idx = tid; idx < 32768; idx += 256)
    ob[idx] *= scal[idx >> 9];                    // L2-resident RMW
}

extern "C" void kernel_launch(void* const* d_in, const int* in_sizes, int n_in,
                              void* d_out, int out_size, void* d_ws, size_t ws_size,
                              hipStream_t stream) {
  const float* x     = (const float*)d_in[0];
  const float* t     = (const float*)d_in[1];
  const float* cent  = (const float*)d_in[2];
  const float* convw = (const float*)d_in[3];
  const float* convb = (const float*)d_in[4];
  const float* lnw   = (const float*)d_in[5];
  const float* lnb   = (const float*)d_in[6];
  const float* w_t   = (const float*)d_in[7];
  const float* b_t   = (const float*)d_in[8];
  const float* w_s   = (const float*)d_in[9];
  const float* b_s   = (const float*)d_in[10];
  const float* w_m   = (const float*)d_in[11];
  const float* b_m   = (const float*)d_in[12];
  const float* w_l   = (const float*)d_in[13];
  const float* b_l   = (const float*)d_in[14];
  const float* accw  = (const float*)d_in[15];
  const float* accb  = (const float*)d_in[16];
  float* ws  = (float*)d_ws;
  float* out = (float*)d_out;

  float* wbs  = ws + OFF_WBS;
  float* wbm  = ws + OFF_WBM;
  float* wbl  = ws + OFF_WBL;
  float* wbt  = ws + OFF_WBT;
  float* beta = ws + OFF_BETA;
  short* cwfh = (short*)(ws + OFF_CWF);
  short* cwfm = (short*)(ws + OFF_CWF + 16384);   // 16384 fl spacing (32768 shorts each)
  short* cwfl = (short*)(ws + OFF_CWF + 32768);
  short* plth = (short*)(ws + OFF_PLTH);
  short* pltl = (short*)(ws + OFF_PLTL);
  short* qth  = (short*)(ws + OFF_QTH);
  short* qtl  = (short*)(ws + OFF_QTL);
  short* pwth = (short*)(ws + OFF_PWTH);
  short* pwtl = (short*)(ws + OFF_PWTL);
  float* PB   = ws + OFF_PB;
  float* pbp  = ws + OFF_PBP;
  float* mur  = ws + OFF_MUR;
  float* xs   = ws + OFF_XS;
  float* cwp2 = ws + OFF_CWP2;
  float* wr   = ws + OFF_WR;       // aliases xs (dead after k_cwg)
  float* wsumb = ws + OFF_WSUM;
  float* centT = ws + OFF_CENTT;

  k_wbar<<<dim3(406), dim3(256), 0, stream>>>(w_s, w_m, w_l, w_t, accw, accb,
                                              b_s, b_m, b_l, b_t,
                                              wbs, wbm, wbl, wbt, beta);
  k_wt<<<dim3(256), dim3(256), 0, stream>>>(convw, cent, cwfh, cwfm, cwfl, centT);
  k_xs<<<dim3(1024), dim3(256), 0, stream>>>(x, xs, mur);
  hipMemsetAsync(ws + OFF_PLTH, 0, (size_t)3244032 * 4, stream);  // pad rows q=49..63
  k_buildP<<<dim3(512), dim3(512), 0, stream>>>(wbs, wbm, wbl, wbt, lnw, lnb,
                                                plth, pltl, qth, qtl,
                                                pwth, pwtl, pbp);
  k_pb<<<dim3(49), dim3(64), 0, stream>>>(pbp, PB);
  k_cwg<<<dim3(3136), dim3(64), 0, stream>>>(xs, t, mur, plth, pltl, qth, qtl,
                                             pwth, pwtl, cwp2);
  k_logits<<<dim3(512), dim3(256), 0, stream>>>(x, cwfh, cwfm, cwfl, convb, cwp2,
                                                beta, PB, wr, wsumb);
  k_vlad<<<dim3(512), dim3(256), 0, stream>>>(x, wr, wsumb, centT, out);
}